// Round 11
// baseline (379.804 us; speedup 1.0000x reference)
//
#include <hip/hip_runtime.h>
#include <hip/hip_bf16.h>
#include <math.h>

// Problem constants (reference: B=2, T=2048, D=1024, H=16, DH=64)
#define B_  2
#define T_  2048
#define D_  1024
#define H_  16
#define DH_ 64
#define WN_ (D_ * D_)   // 1,048,576 elems per weight

typedef __attribute__((ext_vector_type(8))) short bf16x8;
typedef __attribute__((ext_vector_type(4))) float f32x4;
typedef __attribute__((ext_vector_type(16))) float f32x16;

// async global->LDS, 16B per lane; dest = wave-uniform base + lane*16
__device__ __forceinline__ void gll16(const void* g, void* l) {
  __builtin_amdgcn_global_load_lds(
      (const __attribute__((address_space(1))) void*)g,
      (__attribute__((address_space(3))) void*)l, 16, 0, 0);
}

__device__ __forceinline__ void storeC(float* p, float v) { *p = v; }
__device__ __forceinline__ void storeC(__hip_bfloat16* p, float v) {
  *p = __float2bfloat16(v);
}

__device__ __forceinline__ float bf2f(short u) {
  union { unsigned int i; float f; } cv;
  cv.i = ((unsigned int)(unsigned short)u) << 16;
  return cv.f;
}
__device__ __forceinline__ short f2bf(float f) {
  __hip_bfloat16 h = __float2bfloat16(f);
  return *(short*)&h;
}

// ---------------------------------------------------------------------------
// f32 -> bf16 elementwise convert (4 elems/thread)
// ---------------------------------------------------------------------------
__global__ __launch_bounds__(256)
void cvt_f32_bf16(const float* __restrict__ in, __hip_bfloat16* __restrict__ out,
                  int n4) {
  const int i = blockIdx.x * 256 + threadIdx.x;
  if (i >= n4) return;
  const float4 a = ((const float4*)in)[i];
  ushort4 o;
  o.x = (unsigned short)f2bf(a.x);
  o.y = (unsigned short)f2bf(a.y);
  o.z = (unsigned short)f2bf(a.z);
  o.w = (unsigned short)f2bf(a.w);
  *(ushort4*)(out + (size_t)i * 4) = o;
}

// ---------------------------------------------------------------------------
// Wq|Wk|Wv f32 -> one contiguous bf16 [3072][1024]
// ---------------------------------------------------------------------------
__global__ __launch_bounds__(256)
void cvt3_w(const float* __restrict__ Wq, const float* __restrict__ Wk,
            const float* __restrict__ Wv, __hip_bfloat16* __restrict__ out) {
  const int i = blockIdx.x * 256 + threadIdx.x;  // over 3*WN_/4
  const int per = WN_ / 4;                       // 262144 (pow2)
  const int sel = i >> 18;
  const int off = i & (per - 1);
  const float* src = sel == 0 ? Wq : (sel == 1 ? Wk : Wv);
  const float4 a = ((const float4*)src)[off];
  ushort4 o;
  o.x = (unsigned short)f2bf(a.x);
  o.y = (unsigned short)f2bf(a.y);
  o.z = (unsigned short)f2bf(a.z);
  o.w = (unsigned short)f2bf(a.w);
  *(ushort4*)(out + (size_t)sel * WN_ + (size_t)off * 4) = o;
}

// ---------------------------------------------------------------------------
// bf16 MFMA GEMM: C[m,n] = sum_k A[m,k]*W[n,k]; C fp32 or bf16.
// 128x128 tile, BK=32, 256 thr = 4 waves. (verified R6-R10, unchanged)
// ---------------------------------------------------------------------------
template <typename CT>
__global__ __launch_bounds__(256)
void gemm_bf16_mfma(const __hip_bfloat16* __restrict__ A,
                    const __hip_bfloat16* __restrict__ W,
                    CT* __restrict__ C, int M, int N, int K) {
  __shared__ unsigned short As[128 * 32];
  __shared__ unsigned short Bs[128 * 32];
  const int tid = threadIdx.x;
  const int w = tid >> 6;
  const int lane = tid & 63;
  const int lg = lane >> 4;
  const int ln = lane & 15;
  const int wr = w >> 1, wc = w & 1;
  const int row0 = blockIdx.y * 128;
  const int col0 = blockIdx.x * 128;

  const int sr = w * 32 + (lane >> 2);
  const int sp = lane & 3;

  f32x4 acc[4][4];
#pragma unroll
  for (int m = 0; m < 4; ++m)
#pragma unroll
    for (int n = 0; n < 4; ++n) acc[m][n] = (f32x4){0.f, 0.f, 0.f, 0.f};

  for (int k0 = 0; k0 < K; k0 += 32) {
#pragma unroll
    for (int c = 0; c < 2; ++c) {
      const int r = sr + c * 16;
      const int ks = sp ^ ((r >> 1) & 3);
      gll16(A + (size_t)(row0 + r) * K + k0 + ks * 8,
            &As[(w * 32 + c * 16) * 32]);
      gll16(W + (size_t)(col0 + r) * K + k0 + ks * 8,
            &Bs[(w * 32 + c * 16) * 32]);
    }
    __syncthreads();

    bf16x8 af[4], bfr[4];
#pragma unroll
    for (int m = 0; m < 4; ++m) {
      const int r = wr * 64 + m * 16 + ln;
      af[m] = *(const bf16x8*)&As[r * 32 + (lg ^ ((r >> 1) & 3)) * 8];
    }
#pragma unroll
    for (int n = 0; n < 4; ++n) {
      const int r = wc * 64 + n * 16 + ln;
      bfr[n] = *(const bf16x8*)&Bs[r * 32 + (lg ^ ((r >> 1) & 3)) * 8];
    }
#pragma unroll
    for (int m = 0; m < 4; ++m)
#pragma unroll
      for (int n = 0; n < 4; ++n)
        acc[m][n] = __builtin_amdgcn_mfma_f32_16x16x32_bf16(af[m], bfr[n],
                                                            acc[m][n], 0, 0, 0);
    __syncthreads();
  }

#pragma unroll
  for (int m = 0; m < 4; ++m) {
#pragma unroll
    for (int reg = 0; reg < 4; ++reg) {
      CT* crow = C + (size_t)(row0 + wr * 64 + m * 16 + lg * 4 + reg) * N
                 + col0 + wc * 64;
#pragma unroll
      for (int n = 0; n < 4; ++n) storeC(&crow[n * 16 + ln], acc[m][n][reg]);
    }
  }
}

// ---------------------------------------------------------------------------
// Fused RoPE (R11): qkv[:,0:2048] -> Qb row-major [B,T,H,64] AND Kf
// frag-major directly (kf_prep eliminated).  Thread (rest,j): d = j*8..j*8+7
// paired with d+32; frag chunk (ks=j>>1, hb=j&1) and (ks+2, hb).
// ---------------------------------------------------------------------------
__global__ __launch_bounds__(256)
void rope_fused(const __hip_bfloat16* __restrict__ qkv,
                __hip_bfloat16* __restrict__ Qb,
                __hip_bfloat16* __restrict__ Kf) {
  const int idx = blockIdx.x * 256 + threadIdx.x;  // B*T*H*4 threads
  const int j = idx & 3;
  const int rest = idx >> 2;            // (b*T+t)*H + h
  const int h = rest & 15;
  const int row = rest >> 4;            // b*T + t
  const int t = row & (T_ - 1);
  const int b = row >> 11;              // T_=2048

  const size_t src = (size_t)row * 3072 + h * 64 + j * 8;
  bf16x8 qlo = *(const bf16x8*)(qkv + src);
  bf16x8 qhi = *(const bf16x8*)(qkv + src + 32);
  bf16x8 klo = *(const bf16x8*)(qkv + src + 1024);
  bf16x8 khi = *(const bf16x8*)(qkv + src + 1024 + 32);
  bf16x8 qolo, qohi, kolo, kohi;
#pragma unroll
  for (int i = 0; i < 8; ++i) {
    const int d = j * 8 + i;
    const float inv_freq = powf(10000.0f, -(float)d * (1.0f / 32.0f));
    const float ang = (float)t * inv_freq;
    const float c = cosf(ang), s = sinf(ang);
    const float q1 = bf2f(qlo[i]), q2 = bf2f(qhi[i]);
    const float k1 = bf2f(klo[i]), k2 = bf2f(khi[i]);
    qolo[i] = f2bf((q1 * c - q2 * s) * 0.125f);
    qohi[i] = f2bf((q2 * c + q1 * s) * 0.125f);
    kolo[i] = f2bf(k1 * c - k2 * s);
    kohi[i] = f2bf(k2 * c + k1 * s);
  }
  __hip_bfloat16* qdst = Qb + (size_t)rest * 64 + j * 8;
  *(bf16x8*)qdst = qolo;
  *(bf16x8*)(qdst + 32) = qohi;

  const int bh = b * 16 + h, kt = t >> 6, tt = t & 63;
  const int kb2 = tt >> 5, l31 = tt & 31, ks = j >> 1, hb = j & 1;
  __hip_bfloat16* kdst = Kf + (size_t)bh * (T_ * 64) + (size_t)kt * 4096;
  *(bf16x8*)(kdst + ((kb2 * 4 + ks) * 64 + hb * 32 + l31) * 8) = kolo;
  *(bf16x8*)(kdst + ((kb2 * 4 + ks + 2) * 64 + hb * 32 + l31) * 8) = kohi;
}

// ---------------------------------------------------------------------------
// V (qkv cols 2048..3071) -> V^T fragment-major (unchanged from R10).
// ---------------------------------------------------------------------------
__global__ __launch_bounds__(256)
void vf_prep(const __hip_bfloat16* __restrict__ qkv, __hip_bfloat16* __restrict__ Vf) {
  __shared__ unsigned short Ls[64][72];   // [d][t], 144B rows (16B aligned)
  const int kt = blockIdx.x;
  const int bh = blockIdx.y;
  const int b = bh >> 4, h = bh & 15;
  const int tid = threadIdx.x;
  const int rb = tid >> 3, c0 = (tid & 7) * 8;
#pragma unroll
  for (int it = 0; it < 2; ++it) {
    const int r = it * 32 + rb;  // token row in tile
    uint4 x = *(const uint4*)&qkv[(size_t)((size_t)b * T_ + kt * 64 + r) * 3072 +
                                  2048 + h * 64 + c0];
    const unsigned short* xs = (const unsigned short*)&x;
#pragma unroll
    for (int q = 0; q < 8; ++q) Ls[c0 + q][r] = xs[q];
  }
  __syncthreads();
  __hip_bfloat16* dsth = Vf + (size_t)bh * (T_ * 64) + (size_t)kt * 4096;
#pragma unroll
  for (int e = 0; e < 2; ++e) {
    const int g = e * 256 + tid;            // 0..511 frag-groups
    const int lane31 = g & 31, hi = (g >> 5) & 1, ks = (g >> 6) & 3, kb2 = g >> 8;
    bf16x8 x = *(const bf16x8*)&Ls[kb2 * 32 + lane31][ks * 16 + hi * 8];
    *(bf16x8*)(dsth + (size_t)g * 8) = x;   // g*8 == ((kb2*4+ks)*64+hi*32+lane31)*8
  }
}

// ---------------------------------------------------------------------------
// Split-K barrier-free flash attention (R11).
//  Wave = (unit qu, half): processes key-tiles [kt0,kt1) of unit qu with
//  private (m,l,accO); compute core identical to R9/R10-verified code.
//  Block = 4 waves = units {bx, 63-bx} x halves {A,B} -> 33 tiles/block
//  uniform.  Single __syncthreads before the LDS merge (B-half publishes
//  m/l/acc; A-half combines and stores O).  Grid (32,32)=1024 blocks with
//  bijective XCD swizzle: each XCD owns 4 heads (~3.1MB Q+K+V < 4MB L2).
// ---------------------------------------------------------------------------
#define SWZ(row, col) ((col) ^ (((row) & 7) << 3))

struct KV { bf16x8 k[2][4]; bf16x8 v[2][4]; };

__global__ __launch_bounds__(256, 3)
void attn_split(const __hip_bfloat16* __restrict__ Qb,
                const __hip_bfloat16* __restrict__ Kf,
                const __hip_bfloat16* __restrict__ Vf,
                __hip_bfloat16* __restrict__ O) {
  __shared__ unsigned short Ps[4][32 * 64];   // per-wave P strip, 16 KB
  __shared__ float MrgAcc[2][64][33];         // per unit-slot acc publish
  __shared__ float MrgML[2][64][2];           // m, l publish

  // XCD swizzle: id%8 -> XCD (round-robin model); give XCD x heads 4x..4x+3
  const int id = (int)blockIdx.x + 32 * (int)blockIdx.y;  // 0..1023
  const int nid = (id & 7) * 128 + (id >> 3);
  const int bx = nid & 31;        // 0..31
  const int bh = nid >> 5;        // 0..31

  const int tid = threadIdx.x;
  const int w = tid >> 6;
  const int lane = tid & 63;
  const int lq = lane & 31;
  const int hi = lane >> 5;
  const int slot = w >> 1;        // 0: unit L, 1: unit H
  const int half = w & 1;         // 0: first key-range, 1: second

  const int qu = slot ? (63 - bx) : bx;
  const int nt = (qu >> 1) + 1;   // total kv-tiles for this unit
  const int nA = nt - (nt >> 1);  // ceil(nt/2)
  const int kt0 = half ? nA : 0;
  const int kt1 = half ? nt : nA;
  const int q_glob = qu * 32 + lq;

  const int b = bh >> 4, h = bh & 15;
  const size_t headoff = (size_t)b * T_ * D_ + (size_t)h * DH_;
  const __hip_bfloat16* Qg = Qb + headoff;
  const __hip_bfloat16* Kfh = Kf + (size_t)bh * (T_ * 64);
  const __hip_bfloat16* Vfh = Vf + (size_t)bh * (T_ * 64);
  __hip_bfloat16* Og = O + headoff;

  // Q B-frags (col=q, k=d): 4 x 16B  (Qb is [B,T,H,64] row-major)
  bf16x8 qf[4];
#pragma unroll
  for (int ks = 0; ks < 4; ++ks)
    qf[ks] = *(const bf16x8*)(Qg + (size_t)q_glob * D_ + ks * 16 + hi * 8);

  float m_run = -3.0e38f, l_run = 0.f;
  f32x16 accO[2];
#pragma unroll
  for (int reg = 0; reg < 16; ++reg) { accO[0][reg] = 0.f; accO[1][reg] = 0.f; }

  auto load = [&](int kt) {
    KV r;
    const __hip_bfloat16* kp = Kfh + (size_t)kt * 4096;
    const __hip_bfloat16* vp = Vfh + (size_t)kt * 4096;
#pragma unroll
    for (int kb2 = 0; kb2 < 2; ++kb2)
#pragma unroll
      for (int ks = 0; ks < 4; ++ks) {
        r.k[kb2][ks] = *(const bf16x8*)(kp + ((kb2 * 4 + ks) * 64 + lane) * 8);
        r.v[kb2][ks] = *(const bf16x8*)(vp + ((kb2 * 4 + ks) * 64 + lane) * 8);
      }
    return r;
  };

  auto compute = [&](const KV& kv, int kt) {
    // ---- S^T = K · Q^T  (col = q = lq) ----
    f32x16 sf[2];
#pragma unroll
    for (int reg = 0; reg < 16; ++reg) { sf[0][reg] = 0.f; sf[1][reg] = 0.f; }
    const bool last = (kt == nt - 1);
    const bool skip1 = last && !(qu & 1);   // upper key-half fully masked
#pragma unroll
    for (int ks = 0; ks < 4; ++ks)
      sf[0] = __builtin_amdgcn_mfma_f32_32x32x16_bf16(kv.k[0][ks], qf[ks], sf[0], 0, 0, 0);
    if (!skip1) {
#pragma unroll
      for (int ks = 0; ks < 4; ++ks)
        sf[1] = __builtin_amdgcn_mfma_f32_32x32x16_bf16(kv.k[1][ks], qf[ks], sf[1], 0, 0, 0);
    }

    // ---- causal mask (true last tile only) ----
    if (last) {
      const int kv0 = kt * 64;
#pragma unroll
      for (int reg = 0; reg < 16; ++reg) {
        const int krow = (reg & 3) + 8 * (reg >> 2) + 4 * hi;
        if (kv0 + krow > q_glob)      sf[0][reg] = -3.0e38f;
        if (kv0 + 32 + krow > q_glob) sf[1][reg] = -3.0e38f;
      }
    }

    // ---- online softmax (lane-local; one cross-half shfl each) ----
    float pmax = -3.0e38f;
#pragma unroll
    for (int reg = 0; reg < 16; ++reg)
      pmax = fmaxf(pmax, fmaxf(sf[0][reg], sf[1][reg]));
    pmax = fmaxf(pmax, __shfl_xor(pmax, 32, 64));
    const float mnew = fmaxf(m_run, pmax);
    const float alpha = __expf(m_run - mnew);
    m_run = mnew;
    float rsum = 0.f;
#pragma unroll
    for (int reg = 0; reg < 16; ++reg) {
      sf[0][reg] = __expf(sf[0][reg] - mnew);
      sf[1][reg] = __expf(sf[1][reg] - mnew);
      rsum += sf[0][reg] + sf[1][reg];
    }
    rsum += __shfl_xor(rsum, 32, 64);
    l_run = l_run * alpha + rsum;
#pragma unroll
    for (int reg = 0; reg < 16; ++reg) {
      accO[0][reg] *= alpha;
      accO[1][reg] *= alpha;
    }

    // ---- P -> per-wave LDS strip (packed 8B writes) ----
#pragma unroll
    for (int kb2 = 0; kb2 < 2; ++kb2) {
#pragma unroll
      for (int j = 0; j < 4; ++j) {
        uint2 pk;
        pk.x = (unsigned)(unsigned short)f2bf(sf[kb2][4 * j + 0]) |
               ((unsigned)(unsigned short)f2bf(sf[kb2][4 * j + 1]) << 16);
        pk.y = (unsigned)(unsigned short)f2bf(sf[kb2][4 * j + 2]) |
               ((unsigned)(unsigned short)f2bf(sf[kb2][4 * j + 3]) << 16);
        const int col = kb2 * 32 + 8 * j + 4 * hi;
        *(uint2*)&Ps[w][lq * 64 + SWZ(lq, col)] = pk;
      }
    }

    // ---- O^T += V^T · P ----
#pragma unroll
    for (int ks = 0; ks < 4; ++ks) {
      const int c = ks * 16 + hi * 8;
      bf16x8 pb = *(const bf16x8*)&Ps[w][lq * 64 + SWZ(lq, c)];
      accO[0] = __builtin_amdgcn_mfma_f32_32x32x16_bf16(kv.v[0][ks], pb, accO[0], 0, 0, 0);
      accO[1] = __builtin_amdgcn_mfma_f32_32x32x16_bf16(kv.v[1][ks], pb, accO[1], 0, 0, 0);
    }
  };

  // ---- main loop over [kt0, kt1): 2-buffer rotation, loads 1 tile ahead ----
  if (kt0 < kt1) {
    KV bufA = load(kt0), bufB;
    int kt = kt0;
    while (true) {
      if (kt + 1 < kt1) bufB = load(kt + 1);
      compute(bufA, kt);
      ++kt; if (kt == kt1) break;
      if (kt + 1 < kt1) bufA = load(kt + 1);
      compute(bufB, kt);
      ++kt; if (kt == kt1) break;
    }
  }

  // ---- split-K merge: B publishes, barrier, A combines + stores ----
  if (half) {
#pragma unroll
    for (int reg = 0; reg < 16; ++reg) {
      MrgAcc[slot][lane][reg] = accO[0][reg];
      MrgAcc[slot][lane][16 + reg] = accO[1][reg];
    }
    MrgML[slot][lane][0] = m_run;
    MrgML[slot][lane][1] = l_run;
  }
  __syncthreads();
  if (!half) {
    const float mB = MrgML[slot][lane][0];
    const float lB = MrgML[slot][lane][1];
    const float mS = fmaxf(m_run, mB);
    const float aA = __expf(m_run - mS);
    const float aB = __expf(mB - mS);
    const float linv = 1.0f / (l_run * aA + lB * aB);
#pragma unroll
    for (int db = 0; db < 2; ++db) {
#pragma unroll
      for (int j = 0; j < 4; ++j) {
        float o0 = (accO[db][4 * j + 0] * aA + MrgAcc[slot][lane][db * 16 + 4 * j + 0] * aB) * linv;
        float o1 = (accO[db][4 * j + 1] * aA + MrgAcc[slot][lane][db * 16 + 4 * j + 1] * aB) * linv;
        float o2 = (accO[db][4 * j + 2] * aA + MrgAcc[slot][lane][db * 16 + 4 * j + 2] * aB) * linv;
        float o3 = (accO[db][4 * j + 3] * aA + MrgAcc[slot][lane][db * 16 + 4 * j + 3] * aB) * linv;
        uint2 pk;
        pk.x = (unsigned)(unsigned short)f2bf(o0) |
               ((unsigned)(unsigned short)f2bf(o1) << 16);
        pk.y = (unsigned)(unsigned short)f2bf(o2) |
               ((unsigned)(unsigned short)f2bf(o3) << 16);
        const int d = db * 32 + 8 * j + 4 * hi;
        *(uint2*)(Og + (size_t)q_glob * D_ + d) = pk;
      }
    }
  }
}

// ---------------------------------------------------------------------------
// kernel_launch. ws elems (bf16): qkvb 3NE | xb NE | Wqkvb 3WN | qb NE |
// Kf NE | Vf NE  (kb eliminated; peak < R10-proven 65.0 MB).
// aob overlays qkvb; Wob overlays Wqkvb (stream-ordered reuse).
// ---------------------------------------------------------------------------
extern "C" void kernel_launch(void* const* d_in, const int* in_sizes, int n_in,
                              void* d_out, int out_size, void* d_ws, size_t ws_size,
                              hipStream_t stream) {
  const float* x  = (const float*)d_in[0];
  const float* Wq = (const float*)d_in[1];
  const float* Wk = (const float*)d_in[2];
  const float* Wv = (const float*)d_in[3];
  const float* Wo = (const float*)d_in[4];
  float* out = (float*)d_out;

  const size_t NE = (size_t)B_ * T_ * D_;   // 4,194,304
  char* base = (char*)d_ws;
  __hip_bfloat16* qkvb  = (__hip_bfloat16*)base;                          // 3NE
  __hip_bfloat16* xb    = (__hip_bfloat16*)(base + 3 * NE * 2);           // NE
  __hip_bfloat16* Wqkvb = (__hip_bfloat16*)(base + 4 * NE * 2);           // 3WN
  __hip_bfloat16* qb    = (__hip_bfloat16*)(base + 4 * NE * 2 + 3ull * WN_ * 2);
  __hip_bfloat16* Kfb   = qb + NE;
  __hip_bfloat16* Vfb   = Kfb + NE;
  __hip_bfloat16* aob   = qkvb;   // overlays qkvb (dead after rope+vf_prep)
  __hip_bfloat16* Wob   = Wqkvb;  // overlays Wqkvb (dead after gemm_qkv)

  cvt_f32_bf16<<<(int)(NE / 4 / 256), 256, 0, stream>>>(x, xb, (int)(NE / 4));
  cvt3_w<<<3 * WN_ / 4 / 256, 256, 0, stream>>>(Wq, Wk, Wv, Wqkvb);

  const dim3 gq(3 * D_ / 128, (B_ * T_) / 128);  // (24, 32)
  gemm_bf16_mfma<__hip_bfloat16><<<gq, 256, 0, stream>>>(
      xb, Wqkvb, qkvb, B_ * T_, 3 * D_, D_);

  rope_fused<<<(B_ * T_ * H_ * 4) / 256, 256, 0, stream>>>(qkvb, qb, Kfb);
  vf_prep<<<dim3(T_ / 64, B_ * H_), 256, 0, stream>>>(qkvb, Vfb);

  const dim3 ga(32, 32);  // 1024 blocks, XCD-swizzled in-kernel
  attn_split<<<ga, 256, 0, stream>>>(qb, Kfb, Vfb, aob);

  cvt_f32_bf16<<<WN_ / 4 / 256, 256, 0, stream>>>(Wo, Wob, WN_ / 4);

  const dim3 go(D_ / 128, (B_ * T_) / 128);  // (8, 32)
  gemm_bf16_mfma<float><<<go, 256, 0, stream>>>(aob, Wob, out, B_ * T_, D_, D_);
}

// Round 12
// 235.447 us; speedup vs baseline: 1.6131x; 1.6131x over previous
//
#include <hip/hip_runtime.h>
#include <hip/hip_bf16.h>
#include <math.h>

// Problem constants (reference: B=2, T=2048, D=1024, H=16, DH=64)
#define B_  2
#define T_  2048
#define D_  1024
#define H_  16
#define DH_ 64
#define WN_ (D_ * D_)   // 1,048,576 elems per weight

typedef __attribute__((ext_vector_type(8))) short bf16x8;
typedef __attribute__((ext_vector_type(4))) float f32x4;
typedef __attribute__((ext_vector_type(16))) float f32x16;

// async global->LDS, 16B per lane; dest = wave-uniform base + lane*16
__device__ __forceinline__ void gll16(const void* g, void* l) {
  __builtin_amdgcn_global_load_lds(
      (const __attribute__((address_space(1))) void*)g,
      (__attribute__((address_space(3))) void*)l, 16, 0, 0);
}

__device__ __forceinline__ void storeC(float* p, float v) { *p = v; }
__device__ __forceinline__ void storeC(__hip_bfloat16* p, float v) {
  *p = __float2bfloat16(v);
}

__device__ __forceinline__ float bf2f(short u) {
  union { unsigned int i; float f; } cv;
  cv.i = ((unsigned int)(unsigned short)u) << 16;
  return cv.f;
}
__device__ __forceinline__ short f2bf(float f) {
  __hip_bfloat16 h = __float2bfloat16(f);
  return *(short*)&h;
}

// ---------------------------------------------------------------------------
// f32 -> bf16 elementwise convert (4 elems/thread)
// ---------------------------------------------------------------------------
__global__ __launch_bounds__(256)
void cvt_f32_bf16(const float* __restrict__ in, __hip_bfloat16* __restrict__ out,
                  int n4) {
  const int i = blockIdx.x * 256 + threadIdx.x;
  if (i >= n4) return;
  const float4 a = ((const float4*)in)[i];
  ushort4 o;
  o.x = (unsigned short)f2bf(a.x);
  o.y = (unsigned short)f2bf(a.y);
  o.z = (unsigned short)f2bf(a.z);
  o.w = (unsigned short)f2bf(a.w);
  *(ushort4*)(out + (size_t)i * 4) = o;
}

// ---------------------------------------------------------------------------
// Wq|Wk|Wv f32 -> one contiguous bf16 [3072][1024]
// ---------------------------------------------------------------------------
__global__ __launch_bounds__(256)
void cvt3_w(const float* __restrict__ Wq, const float* __restrict__ Wk,
            const float* __restrict__ Wv, __hip_bfloat16* __restrict__ out) {
  const int i = blockIdx.x * 256 + threadIdx.x;  // over 3*WN_/4
  const int per = WN_ / 4;                       // 262144 (pow2)
  const int sel = i >> 18;
  const int off = i & (per - 1);
  const float* src = sel == 0 ? Wq : (sel == 1 ? Wk : Wv);
  const float4 a = ((const float4*)src)[off];
  ushort4 o;
  o.x = (unsigned short)f2bf(a.x);
  o.y = (unsigned short)f2bf(a.y);
  o.z = (unsigned short)f2bf(a.z);
  o.w = (unsigned short)f2bf(a.w);
  *(ushort4*)(out + (size_t)sel * WN_ + (size_t)off * 4) = o;
}

// ---------------------------------------------------------------------------
// bf16 MFMA GEMM: C[m,n] = sum_k A[m,k]*W[n,k]; C fp32 or bf16.
// 128x128 tile, BK=32, 256 thr = 4 waves. (verified R6-R10, unchanged)
// ---------------------------------------------------------------------------
template <typename CT>
__global__ __launch_bounds__(256)
void gemm_bf16_mfma(const __hip_bfloat16* __restrict__ A,
                    const __hip_bfloat16* __restrict__ W,
                    CT* __restrict__ C, int M, int N, int K) {
  __shared__ unsigned short As[128 * 32];
  __shared__ unsigned short Bs[128 * 32];
  const int tid = threadIdx.x;
  const int w = tid >> 6;
  const int lane = tid & 63;
  const int lg = lane >> 4;
  const int ln = lane & 15;
  const int wr = w >> 1, wc = w & 1;
  const int row0 = blockIdx.y * 128;
  const int col0 = blockIdx.x * 128;

  const int sr = w * 32 + (lane >> 2);
  const int sp = lane & 3;

  f32x4 acc[4][4];
#pragma unroll
  for (int m = 0; m < 4; ++m)
#pragma unroll
    for (int n = 0; n < 4; ++n) acc[m][n] = (f32x4){0.f, 0.f, 0.f, 0.f};

  for (int k0 = 0; k0 < K; k0 += 32) {
#pragma unroll
    for (int c = 0; c < 2; ++c) {
      const int r = sr + c * 16;
      const int ks = sp ^ ((r >> 1) & 3);
      gll16(A + (size_t)(row0 + r) * K + k0 + ks * 8,
            &As[(w * 32 + c * 16) * 32]);
      gll16(W + (size_t)(col0 + r) * K + k0 + ks * 8,
            &Bs[(w * 32 + c * 16) * 32]);
    }
    __syncthreads();

    bf16x8 af[4], bfr[4];
#pragma unroll
    for (int m = 0; m < 4; ++m) {
      const int r = wr * 64 + m * 16 + ln;
      af[m] = *(const bf16x8*)&As[r * 32 + (lg ^ ((r >> 1) & 3)) * 8];
    }
#pragma unroll
    for (int n = 0; n < 4; ++n) {
      const int r = wc * 64 + n * 16 + ln;
      bfr[n] = *(const bf16x8*)&Bs[r * 32 + (lg ^ ((r >> 1) & 3)) * 8];
    }
#pragma unroll
    for (int m = 0; m < 4; ++m)
#pragma unroll
      for (int n = 0; n < 4; ++n)
        acc[m][n] = __builtin_amdgcn_mfma_f32_16x16x32_bf16(af[m], bfr[n],
                                                            acc[m][n], 0, 0, 0);
    __syncthreads();
  }

#pragma unroll
  for (int m = 0; m < 4; ++m) {
#pragma unroll
    for (int reg = 0; reg < 4; ++reg) {
      CT* crow = C + (size_t)(row0 + wr * 64 + m * 16 + lg * 4 + reg) * N
                 + col0 + wc * 64;
#pragma unroll
      for (int n = 0; n < 4; ++n) storeC(&crow[n * 16 + ln], acc[m][n][reg]);
    }
  }
}

// ---------------------------------------------------------------------------
// Fused RoPE: qkv[:,0:2048] -> Qb row-major [B,T,H,64] AND Kf frag-major.
// (verified R11, unchanged)
// ---------------------------------------------------------------------------
__global__ __launch_bounds__(256)
void rope_fused(const __hip_bfloat16* __restrict__ qkv,
                __hip_bfloat16* __restrict__ Qb,
                __hip_bfloat16* __restrict__ Kf) {
  const int idx = blockIdx.x * 256 + threadIdx.x;  // B*T*H*4 threads
  const int j = idx & 3;
  const int rest = idx >> 2;            // (b*T+t)*H + h
  const int h = rest & 15;
  const int row = rest >> 4;            // b*T + t
  const int t = row & (T_ - 1);
  const int b = row >> 11;              // T_=2048

  const size_t src = (size_t)row * 3072 + h * 64 + j * 8;
  bf16x8 qlo = *(const bf16x8*)(qkv + src);
  bf16x8 qhi = *(const bf16x8*)(qkv + src + 32);
  bf16x8 klo = *(const bf16x8*)(qkv + src + 1024);
  bf16x8 khi = *(const bf16x8*)(qkv + src + 1024 + 32);
  bf16x8 qolo, qohi, kolo, kohi;
#pragma unroll
  for (int i = 0; i < 8; ++i) {
    const int d = j * 8 + i;
    const float inv_freq = powf(10000.0f, -(float)d * (1.0f / 32.0f));
    const float ang = (float)t * inv_freq;
    const float c = cosf(ang), s = sinf(ang);
    const float q1 = bf2f(qlo[i]), q2 = bf2f(qhi[i]);
    const float k1 = bf2f(klo[i]), k2 = bf2f(khi[i]);
    qolo[i] = f2bf((q1 * c - q2 * s) * 0.125f);
    qohi[i] = f2bf((q2 * c + q1 * s) * 0.125f);
    kolo[i] = f2bf(k1 * c - k2 * s);
    kohi[i] = f2bf(k2 * c + k1 * s);
  }
  __hip_bfloat16* qdst = Qb + (size_t)rest * 64 + j * 8;
  *(bf16x8*)qdst = qolo;
  *(bf16x8*)(qdst + 32) = qohi;

  const int bh = b * 16 + h, kt = t >> 6, tt = t & 63;
  const int kb2 = tt >> 5, l31 = tt & 31, ks = j >> 1, hb = j & 1;
  __hip_bfloat16* kdst = Kf + (size_t)bh * (T_ * 64) + (size_t)kt * 4096;
  *(bf16x8*)(kdst + ((kb2 * 4 + ks) * 64 + hb * 32 + l31) * 8) = kolo;
  *(bf16x8*)(kdst + ((kb2 * 4 + ks + 2) * 64 + hb * 32 + l31) * 8) = kohi;
}

// ---------------------------------------------------------------------------
// V (qkv cols 2048..3071) -> V^T fragment-major (unchanged from R10/R11).
// ---------------------------------------------------------------------------
__global__ __launch_bounds__(256)
void vf_prep(const __hip_bfloat16* __restrict__ qkv, __hip_bfloat16* __restrict__ Vf) {
  __shared__ unsigned short Ls[64][72];   // [d][t], 144B rows (16B aligned)
  const int kt = blockIdx.x;
  const int bh = blockIdx.y;
  const int b = bh >> 4, h = bh & 15;
  const int tid = threadIdx.x;
  const int rb = tid >> 3, c0 = (tid & 7) * 8;
#pragma unroll
  for (int it = 0; it < 2; ++it) {
    const int r = it * 32 + rb;  // token row in tile
    uint4 x = *(const uint4*)&qkv[(size_t)((size_t)b * T_ + kt * 64 + r) * 3072 +
                                  2048 + h * 64 + c0];
    const unsigned short* xs = (const unsigned short*)&x;
#pragma unroll
    for (int q = 0; q < 8; ++q) Ls[c0 + q][r] = xs[q];
  }
  __syncthreads();
  __hip_bfloat16* dsth = Vf + (size_t)bh * (T_ * 64) + (size_t)kt * 4096;
#pragma unroll
  for (int e = 0; e < 2; ++e) {
    const int g = e * 256 + tid;            // 0..511 frag-groups
    const int lane31 = g & 31, hi = (g >> 5) & 1, ks = (g >> 6) & 3, kb2 = g >> 8;
    bf16x8 x = *(const bf16x8*)&Ls[kb2 * 32 + lane31][ks * 16 + hi * 8];
    *(bf16x8*)(dsth + (size_t)g * 8) = x;   // g*8 == ((kb2*4+ks)*64+hi*32+lane31)*8
  }
}

// ---------------------------------------------------------------------------
// Split-K barrier-free flash attention (R11 structure; R12 fix:
// __launch_bounds__(256,2) -- R11's (256,3) capped VGPR at 84 and spilled
// the KV double-buffer to scratch (355MB writes, 3.3x regression).
// ---------------------------------------------------------------------------
#define SWZ(row, col) ((col) ^ (((row) & 7) << 3))

struct KV { bf16x8 k[2][4]; bf16x8 v[2][4]; };

__global__ __launch_bounds__(256, 2)
void attn_split(const __hip_bfloat16* __restrict__ Qb,
                const __hip_bfloat16* __restrict__ Kf,
                const __hip_bfloat16* __restrict__ Vf,
                __hip_bfloat16* __restrict__ O) {
  __shared__ unsigned short Ps[4][32 * 64];   // per-wave P strip, 16 KB
  __shared__ float MrgAcc[2][64][33];         // per unit-slot acc publish
  __shared__ float MrgML[2][64][2];           // m, l publish

  // XCD swizzle: id%8 -> XCD (round-robin model); give XCD x heads 4x..4x+3
  const int id = (int)blockIdx.x + 32 * (int)blockIdx.y;  // 0..1023
  const int nid = (id & 7) * 128 + (id >> 3);
  const int bx = nid & 31;        // 0..31
  const int bh = nid >> 5;        // 0..31

  const int tid = threadIdx.x;
  const int w = tid >> 6;
  const int lane = tid & 63;
  const int lq = lane & 31;
  const int hi = lane >> 5;
  const int slot = w >> 1;        // 0: unit L, 1: unit H
  const int half = w & 1;         // 0: first key-range, 1: second

  const int qu = slot ? (63 - bx) : bx;
  const int nt = (qu >> 1) + 1;   // total kv-tiles for this unit
  const int nA = nt - (nt >> 1);  // ceil(nt/2)
  const int kt0 = half ? nA : 0;
  const int kt1 = half ? nt : nA;
  const int q_glob = qu * 32 + lq;

  const int b = bh >> 4, h = bh & 15;
  const size_t headoff = (size_t)b * T_ * D_ + (size_t)h * DH_;
  const __hip_bfloat16* Qg = Qb + headoff;
  const __hip_bfloat16* Kfh = Kf + (size_t)bh * (T_ * 64);
  const __hip_bfloat16* Vfh = Vf + (size_t)bh * (T_ * 64);
  __hip_bfloat16* Og = O + headoff;

  // Q B-frags (col=q, k=d): 4 x 16B  (Qb is [B,T,H,64] row-major)
  bf16x8 qf[4];
#pragma unroll
  for (int ks = 0; ks < 4; ++ks)
    qf[ks] = *(const bf16x8*)(Qg + (size_t)q_glob * D_ + ks * 16 + hi * 8);

  float m_run = -3.0e38f, l_run = 0.f;
  f32x16 accO[2];
#pragma unroll
  for (int reg = 0; reg < 16; ++reg) { accO[0][reg] = 0.f; accO[1][reg] = 0.f; }

  auto load = [&](int kt) {
    KV r;
    const __hip_bfloat16* kp = Kfh + (size_t)kt * 4096;
    const __hip_bfloat16* vp = Vfh + (size_t)kt * 4096;
#pragma unroll
    for (int kb2 = 0; kb2 < 2; ++kb2)
#pragma unroll
      for (int ks = 0; ks < 4; ++ks) {
        r.k[kb2][ks] = *(const bf16x8*)(kp + ((kb2 * 4 + ks) * 64 + lane) * 8);
        r.v[kb2][ks] = *(const bf16x8*)(vp + ((kb2 * 4 + ks) * 64 + lane) * 8);
      }
    return r;
  };

  auto compute = [&](const KV& kv, int kt) {
    // ---- S^T = K · Q^T  (col = q = lq) ----
    f32x16 sf[2];
#pragma unroll
    for (int reg = 0; reg < 16; ++reg) { sf[0][reg] = 0.f; sf[1][reg] = 0.f; }
    const bool last = (kt == nt - 1);
    const bool skip1 = last && !(qu & 1);   // upper key-half fully masked
#pragma unroll
    for (int ks = 0; ks < 4; ++ks)
      sf[0] = __builtin_amdgcn_mfma_f32_32x32x16_bf16(kv.k[0][ks], qf[ks], sf[0], 0, 0, 0);
    if (!skip1) {
#pragma unroll
      for (int ks = 0; ks < 4; ++ks)
        sf[1] = __builtin_amdgcn_mfma_f32_32x32x16_bf16(kv.k[1][ks], qf[ks], sf[1], 0, 0, 0);
    }

    // ---- causal mask (true last tile only) ----
    if (last) {
      const int kv0 = kt * 64;
#pragma unroll
      for (int reg = 0; reg < 16; ++reg) {
        const int krow = (reg & 3) + 8 * (reg >> 2) + 4 * hi;
        if (kv0 + krow > q_glob)      sf[0][reg] = -3.0e38f;
        if (kv0 + 32 + krow > q_glob) sf[1][reg] = -3.0e38f;
      }
    }

    // ---- online softmax (lane-local; one cross-half shfl each) ----
    float pmax = -3.0e38f;
#pragma unroll
    for (int reg = 0; reg < 16; ++reg)
      pmax = fmaxf(pmax, fmaxf(sf[0][reg], sf[1][reg]));
    pmax = fmaxf(pmax, __shfl_xor(pmax, 32, 64));
    const float mnew = fmaxf(m_run, pmax);
    const float alpha = __expf(m_run - mnew);
    m_run = mnew;
    float rsum = 0.f;
#pragma unroll
    for (int reg = 0; reg < 16; ++reg) {
      sf[0][reg] = __expf(sf[0][reg] - mnew);
      sf[1][reg] = __expf(sf[1][reg] - mnew);
      rsum += sf[0][reg] + sf[1][reg];
    }
    rsum += __shfl_xor(rsum, 32, 64);
    l_run = l_run * alpha + rsum;
#pragma unroll
    for (int reg = 0; reg < 16; ++reg) {
      accO[0][reg] *= alpha;
      accO[1][reg] *= alpha;
    }

    // ---- P -> per-wave LDS strip (packed 8B writes) ----
#pragma unroll
    for (int kb2 = 0; kb2 < 2; ++kb2) {
#pragma unroll
      for (int j = 0; j < 4; ++j) {
        uint2 pk;
        pk.x = (unsigned)(unsigned short)f2bf(sf[kb2][4 * j + 0]) |
               ((unsigned)(unsigned short)f2bf(sf[kb2][4 * j + 1]) << 16);
        pk.y = (unsigned)(unsigned short)f2bf(sf[kb2][4 * j + 2]) |
               ((unsigned)(unsigned short)f2bf(sf[kb2][4 * j + 3]) << 16);
        const int col = kb2 * 32 + 8 * j + 4 * hi;
        *(uint2*)&Ps[w][lq * 64 + SWZ(lq, col)] = pk;
      }
    }

    // ---- O^T += V^T · P ----
#pragma unroll
    for (int ks = 0; ks < 4; ++ks) {
      const int c = ks * 16 + hi * 8;
      bf16x8 pb = *(const bf16x8*)&Ps[w][lq * 64 + SWZ(lq, c)];
      accO[0] = __builtin_amdgcn_mfma_f32_32x32x16_bf16(kv.v[0][ks], pb, accO[0], 0, 0, 0);
      accO[1] = __builtin_amdgcn_mfma_f32_32x32x16_bf16(kv.v[1][ks], pb, accO[1], 0, 0, 0);
    }
  };

  // ---- main loop over [kt0, kt1): 2-buffer rotation, loads 1 tile ahead ----
  if (kt0 < kt1) {
    KV bufA = load(kt0), bufB;
    int kt = kt0;
    while (true) {
      if (kt + 1 < kt1) bufB = load(kt + 1);
      compute(bufA, kt);
      ++kt; if (kt == kt1) break;
      if (kt + 1 < kt1) bufA = load(kt + 1);
      compute(bufB, kt);
      ++kt; if (kt == kt1) break;
    }
  }

  // ---- split-K merge: B publishes, barrier, A combines + stores ----
  if (half) {
#pragma unroll
    for (int reg = 0; reg < 16; ++reg) {
      MrgAcc[slot][lane][reg] = accO[0][reg];
      MrgAcc[slot][lane][16 + reg] = accO[1][reg];
    }
    MrgML[slot][lane][0] = m_run;
    MrgML[slot][lane][1] = l_run;
  }
  __syncthreads();
  if (!half) {
    const float mB = MrgML[slot][lane][0];
    const float lB = MrgML[slot][lane][1];
    const float mS = fmaxf(m_run, mB);
    const float aA = __expf(m_run - mS);
    const float aB = __expf(mB - mS);
    const float linv = 1.0f / (l_run * aA + lB * aB);
#pragma unroll
    for (int db = 0; db < 2; ++db) {
#pragma unroll
      for (int j = 0; j < 4; ++j) {
        float o0 = (accO[db][4 * j + 0] * aA + MrgAcc[slot][lane][db * 16 + 4 * j + 0] * aB) * linv;
        float o1 = (accO[db][4 * j + 1] * aA + MrgAcc[slot][lane][db * 16 + 4 * j + 1] * aB) * linv;
        float o2 = (accO[db][4 * j + 2] * aA + MrgAcc[slot][lane][db * 16 + 4 * j + 2] * aB) * linv;
        float o3 = (accO[db][4 * j + 3] * aA + MrgAcc[slot][lane][db * 16 + 4 * j + 3] * aB) * linv;
        uint2 pk;
        pk.x = (unsigned)(unsigned short)f2bf(o0) |
               ((unsigned)(unsigned short)f2bf(o1) << 16);
        pk.y = (unsigned)(unsigned short)f2bf(o2) |
               ((unsigned)(unsigned short)f2bf(o3) << 16);
        const int d = db * 32 + 8 * j + 4 * hi;
        *(uint2*)(Og + (size_t)q_glob * D_ + d) = pk;
      }
    }
  }
}

// ---------------------------------------------------------------------------
// kernel_launch. ws elems (bf16): qkvb 3NE | xb NE | Wqkvb 3WN | qb NE |
// Kf NE | Vf NE  (peak < R10-proven 65.0 MB).
// aob overlays qkvb; Wob overlays Wqkvb (stream-ordered reuse).
// ---------------------------------------------------------------------------
extern "C" void kernel_launch(void* const* d_in, const int* in_sizes, int n_in,
                              void* d_out, int out_size, void* d_ws, size_t ws_size,
                              hipStream_t stream) {
  const float* x  = (const float*)d_in[0];
  const float* Wq = (const float*)d_in[1];
  const float* Wk = (const float*)d_in[2];
  const float* Wv = (const float*)d_in[3];
  const float* Wo = (const float*)d_in[4];
  float* out = (float*)d_out;

  const size_t NE = (size_t)B_ * T_ * D_;   // 4,194,304
  char* base = (char*)d_ws;
  __hip_bfloat16* qkvb  = (__hip_bfloat16*)base;                          // 3NE
  __hip_bfloat16* xb    = (__hip_bfloat16*)(base + 3 * NE * 2);           // NE
  __hip_bfloat16* Wqkvb = (__hip_bfloat16*)(base + 4 * NE * 2);           // 3WN
  __hip_bfloat16* qb    = (__hip_bfloat16*)(base + 4 * NE * 2 + 3ull * WN_ * 2);
  __hip_bfloat16* Kfb   = qb + NE;
  __hip_bfloat16* Vfb   = Kfb + NE;
  __hip_bfloat16* aob   = qkvb;   // overlays qkvb (dead after rope+vf_prep)
  __hip_bfloat16* Wob   = Wqkvb;  // overlays Wqkvb (dead after gemm_qkv)

  cvt_f32_bf16<<<(int)(NE / 4 / 256), 256, 0, stream>>>(x, xb, (int)(NE / 4));
  cvt3_w<<<3 * WN_ / 4 / 256, 256, 0, stream>>>(Wq, Wk, Wv, Wqkvb);

  const dim3 gq(3 * D_ / 128, (B_ * T_) / 128);  // (24, 32)
  gemm_bf16_mfma<__hip_bfloat16><<<gq, 256, 0, stream>>>(
      xb, Wqkvb, qkvb, B_ * T_, 3 * D_, D_);

  rope_fused<<<(B_ * T_ * H_ * 4) / 256, 256, 0, stream>>>(qkvb, qb, Kfb);
  vf_prep<<<dim3(T_ / 64, B_ * H_), 256, 0, stream>>>(qkvb, Vfb);

  const dim3 ga(32, 32);  // 1024 blocks, XCD-swizzled in-kernel
  attn_split<<<ga, 256, 0, stream>>>(qb, Kfb, Vfb, aob);

  cvt_f32_bf16<<<WN_ / 4 / 256, 256, 0, stream>>>(Wo, Wob, WN_ / 4);

  const dim3 go(D_ / 128, (B_ * T_) / 128);  // (8, 32)
  gemm_bf16_mfma<float><<<go, 256, 0, stream>>>(aob, Wob, out, B_ * T_, D_, D_);
}